// Round 4
// baseline (355.400 us; speedup 1.0000x reference)
//
#include <hip/hip_runtime.h>

#define NN 50000
#define NE 400000
#define INF 768
#define HF 16
#define OF 21
#define ELLW 40   // Poisson(8) max-degree guard: P(deg>=40 anywhere) ~ 1e-11

#define FMA4(ACC, SS, VV) { (ACC).x += (SS)*(VV).x; (ACC).y += (SS)*(VV).y; \
                            (ACC).z += (SS)*(VV).z; (ACC).w += (SS)*(VV).w; }

// -----------------------------------------------------------------------------
// ELL build: cnt[d] = in-degree, ell[d*ELLW+i] = src of i-th edge into d.
// -----------------------------------------------------------------------------
__global__ __launch_bounds__(256) void scatter_kernel(const int* __restrict__ src,
                                                      const int* __restrict__ dst,
                                                      int* __restrict__ cnt,
                                                      int* __restrict__ ell) {
    int e = blockIdx.x * 256 + threadIdx.x;
    if (e >= NE) return;
    int d = dst[e];
    int pos = atomicAdd(&cnt[d], 1);
    if (pos < ELLW) ell[d * ELLW + pos] = src[e];
}

// -----------------------------------------------------------------------------
// GEMM1: P = F @ W1. One row per lane, block = 1 wave (64 rows), grid 782
// (~3 blocks/CU, balanced). W1 in LDS row-major [k][j]; every compute-loop
// ds_read_b128 is WAVE-UNIFORM -> broadcast, zero bank conflicts (round-3's
// 2.1e7-conflict / LDS-issue bottleneck came from per-lane-different W1
// addresses). Feature row streamed with a 4-deep float4 register prefetch.
// -----------------------------------------------------------------------------
__global__ __launch_bounds__(64) void gemm1_kernel(const float* __restrict__ F,
                                                   const float* __restrict__ W1,
                                                   float* __restrict__ P) {
    __shared__ float W1s[INF * HF];   // 48 KB -> 3 blocks/CU

    const int lane = threadIdx.x;
    {   // coalesced one-shot stage, layout identical to global
        const float4* s = (const float4*)W1;
        float4* d = (float4*)W1s;
        for (int i = lane; i < (INF * HF) / 4; i += 64) d[i] = s[i];
    }
    __syncthreads();

    int row = blockIdx.x * 64 + lane;
    const bool act = row < NN;
    if (!act) row = NN - 1;
    const float4* fr = (const float4*)(F + (size_t)row * INF);

    float4 acc0 = {0,0,0,0}, acc1 = {0,0,0,0}, acc2 = {0,0,0,0}, acc3 = {0,0,0,0};
    float4 buf[4];
#pragma unroll
    for (int i = 0; i < 4; ++i) buf[i] = fr[i];

#pragma unroll 4
    for (int c = 0; c < INF / 4; ++c) {
        float4 fv = buf[c & 3];
        if (c + 4 < INF / 4) buf[c & 3] = fr[c + 4];   // guard: last row OOB
        const int kb = c * 4;
#pragma unroll
        for (int m = 0; m < 4; ++m) {
            const float fm = (m == 0) ? fv.x : (m == 1) ? fv.y : (m == 2) ? fv.z : fv.w;
            const float4* wrow = (const float4*)&W1s[(kb + m) * HF];  // uniform addr
            float4 w0 = wrow[0], w1 = wrow[1], w2 = wrow[2], w3 = wrow[3];
            FMA4(acc0, fm, w0);
            FMA4(acc1, fm, w1);
            FMA4(acc2, fm, w2);
            FMA4(acc3, fm, w3);
        }
    }

    if (act) {
        float4* op = (float4*)(P + (size_t)row * HF);
        op[0] = acc0; op[1] = acc1; op[2] = acc2; op[3] = acc3;
    }
}

// -----------------------------------------------------------------------------
// agg1: A1[n] = sum_{e into n} P[src[e]]. 16 lanes per node: 4 edge-subgroups
// (es) x 4 float4-lanes (q). Dependent-load chain = ceil(deg/4) ~ 2 instead of
// 8; 12.5k waves for latency hiding. Butterfly xor 4,8 merges edge groups.
// -----------------------------------------------------------------------------
__global__ __launch_bounds__(256) void agg1_kernel(const float* __restrict__ P,
                                                   const int* __restrict__ cnt,
                                                   const int* __restrict__ ell,
                                                   float* __restrict__ A1) {
    int g = blockIdx.x * 256 + threadIdx.x;
    int node = g >> 4;
    if (node >= NN) return;
    const int l = g & 15, es = l >> 2, q = l & 3;
    int c = cnt[node]; if (c > ELLW) c = ELLW;
    const int* ep = ell + node * ELLW;

    float4 v = {0,0,0,0};
    for (int i = es; i < c; i += 4) {
        int s = ep[i];
        float4 p = *(const float4*)(P + (size_t)s * HF + q * 4);
        v.x += p.x; v.y += p.y; v.z += p.z; v.w += p.w;
    }
#define BFLY2(VAL) { VAL += __shfl_xor(VAL, 4); VAL += __shfl_xor(VAL, 8); }
    BFLY2(v.x) BFLY2(v.y) BFLY2(v.z) BFLY2(v.w)
#undef BFLY2
    if (es == 0)
        *(float4*)(A1 + (size_t)node * HF + q * 4) = v;
}

// -----------------------------------------------------------------------------
// agg2 + output GEMM fused: A2[n] = sum relu(A1[src]+b1) (16 lanes/node as
// above), then out[n] = A2 @ W2 + b2 via per-q partials + xor 1,2 butterfly.
// -----------------------------------------------------------------------------
__global__ __launch_bounds__(256) void agg2out_kernel(const float* __restrict__ A1,
                                                      const float* __restrict__ b1,
                                                      const int* __restrict__ cnt,
                                                      const int* __restrict__ ell,
                                                      const float* __restrict__ W2,
                                                      const float* __restrict__ b2,
                                                      float* __restrict__ out) {
    __shared__ float W2s[HF * OF];
    __shared__ float b2s[OF];
    const int t = threadIdx.x;
    for (int i = t; i < HF * OF; i += 256) W2s[i] = W2[i];
    if (t < OF) b2s[t] = b2[t];
    __syncthreads();

    int g = blockIdx.x * 256 + t;
    int node = g >> 4;
    if (node >= NN) return;
    const int l = g & 15, es = l >> 2, q = l & 3;

    const float4 bb = *(const float4*)(b1 + q * 4);
    int c = cnt[node]; if (c > ELLW) c = ELLW;
    const int* ep = ell + node * ELLW;

    float4 v = {0,0,0,0};
    for (int i = es; i < c; i += 4) {
        int s = ep[i];
        float4 h = *(const float4*)(A1 + (size_t)s * HF + q * 4);
        h.x = fmaxf(h.x + bb.x, 0.0f);
        h.y = fmaxf(h.y + bb.y, 0.0f);
        h.z = fmaxf(h.z + bb.z, 0.0f);
        h.w = fmaxf(h.w + bb.w, 0.0f);
        v.x += h.x; v.y += h.y; v.z += h.z; v.w += h.w;
    }
#define BFLY2(VAL) { VAL += __shfl_xor(VAL, 4); VAL += __shfl_xor(VAL, 8); }
    BFLY2(v.x) BFLY2(v.y) BFLY2(v.z) BFLY2(v.w)
#undef BFLY2

    // out partials over this lane's 4 hidden dims (j = 4q..4q+3)
    const float* w0 = W2s + (q * 4 + 0) * OF;
    const float* w1 = W2s + (q * 4 + 1) * OF;
    const float* w2 = W2s + (q * 4 + 2) * OF;
    const float* w3 = W2s + (q * 4 + 3) * OF;
    float o[OF];
#pragma unroll
    for (int cc = 0; cc < OF; ++cc)
        o[cc] = v.x * w0[cc] + v.y * w1[cc] + v.z * w2[cc] + v.w * w3[cc];
#pragma unroll
    for (int cc = 0; cc < OF; ++cc) {
        o[cc] += __shfl_xor(o[cc], 1);
        o[cc] += __shfl_xor(o[cc], 2);
    }
    if (es == 0) {
        float* op = out + (size_t)node * OF;
        for (int cc = q; cc < OF; cc += 4) op[cc] = o[cc] + b2s[cc];
    }
}

extern "C" void kernel_launch(void* const* d_in, const int* in_sizes, int n_in,
                              void* d_out, int out_size, void* d_ws, size_t ws_size,
                              hipStream_t stream) {
    const float* F   = (const float*)d_in[0];
    const float* W1  = (const float*)d_in[1];
    const float* b1  = (const float*)d_in[2];
    const float* W2  = (const float*)d_in[3];
    const float* b2  = (const float*)d_in[4];
    const int*   src = (const int*)d_in[5];
    const int*   dst = (const int*)d_in[6];
    float* out = (float*)d_out;

    char* ws = (char*)d_ws;
    int*   cnt = (int*)(ws);                       // 200,000 B
    int*   ell = (int*)(ws + 200192);              // 8,000,000 B
    float* P   = (float*)(ws + 8200192);           // 3,200,000 B
    float* A1  = (float*)(ws + 11400192);          // 3,200,000 B

    (void)hipMemsetAsync(cnt, 0, NN * sizeof(int), stream);
    scatter_kernel<<<(NE + 255) / 256, 256, 0, stream>>>(src, dst, cnt, ell);
    gemm1_kernel<<<(NN + 63) / 64, 64, 0, stream>>>(F, W1, P);
    agg1_kernel<<<(NN * 16 + 255) / 256, 256, 0, stream>>>(P, cnt, ell, A1);
    agg2out_kernel<<<(NN * 16 + 255) / 256, 256, 0, stream>>>(A1, b1, cnt, ell, W2, b2, out);
}

// Round 5
// 314.074 us; speedup vs baseline: 1.1316x; 1.1316x over previous
//
#include <hip/hip_runtime.h>

#define NN 50000
#define NE 400000
#define INF 768
#define HF 16
#define OF 21
#define ELLW 40   // Poisson(8) max-degree guard: P(deg>=40 anywhere) ~ 1e-11

#define FMA4(ACC, SS, VV) { (ACC).x += (SS)*(VV).x; (ACC).y += (SS)*(VV).y; \
                            (ACC).z += (SS)*(VV).z; (ACC).w += (SS)*(VV).w; }

// -----------------------------------------------------------------------------
// ELL build: cnt[d] = in-degree, ell[d*ELLW+i] = src of i-th edge into d.
// -----------------------------------------------------------------------------
__global__ __launch_bounds__(256) void scatter_kernel(const int* __restrict__ src,
                                                      const int* __restrict__ dst,
                                                      int* __restrict__ cnt,
                                                      int* __restrict__ ell) {
    int e = blockIdx.x * 256 + threadIdx.x;
    if (e >= NE) return;
    int d = dst[e];
    int pos = atomicAdd(&cnt[d], 1);
    if (pos < ELLW) ell[d * ELLW + pos] = src[e];
}

// -----------------------------------------------------------------------------
// GEMM1: P = F @ W1  (50000x768 @ 768x16).
// Round-4 lesson: broadcast W1-in-LDS is conflict-free but block=64 + 48KB LDS
// = 3 waves/CU -> latency-bound (Occ 5.7%). Fix: 8 waves SHARE the 48KB —
// block=512, wave w owns k-slice [w*96, w*96+96) (its own LDS plane, addresses
// still wave-uniform -> broadcast, 0 conflicts). 3 blocks/CU = 24 waves/CU.
// Cross-wave k-reduction ALIASES the W1 LDS (barrier-protected reuse) so LDS
// stays 48KB. 8-deep float4 prefetch per lane streams F.
// -----------------------------------------------------------------------------
__global__ __launch_bounds__(512, 6) void gemm1_kernel(const float* __restrict__ F,
                                                       const float* __restrict__ W1,
                                                       float* __restrict__ P) {
    __shared__ float smem[INF * HF];   // 48 KB: W1 [k][j] planes, later red[8][64][16]

    const int t = threadIdx.x;
    {   // coalesced one-shot stage, layout identical to global ([k][j])
        const float4* s = (const float4*)W1;
        float4* d = (float4*)smem;
        for (int i = t; i < (INF * HF) / 4; i += 512) d[i] = s[i];
    }
    __syncthreads();

    const int w = t >> 6, lane = t & 63;
    int row = blockIdx.x * 64 + lane;
    const bool act = row < NN;
    if (!act) row = NN - 1;

    const float4* fr = (const float4*)(F + (size_t)row * INF + w * 96);
    const float* wbase = smem + w * 96 * HF;   // this wave's k-plane [96][16]

    float4 acc0 = {0,0,0,0}, acc1 = {0,0,0,0}, acc2 = {0,0,0,0}, acc3 = {0,0,0,0};
    float4 buf[8];
#pragma unroll
    for (int i = 0; i < 8; ++i) buf[i] = fr[i];

#pragma unroll
    for (int c = 0; c < 24; ++c) {
        float4 fv = buf[c & 7];
        if (c + 8 < 24) buf[c & 7] = fr[c + 8];
        const float* wr = wbase + c * 4 * HF;
#pragma unroll
        for (int m = 0; m < 4; ++m) {
            const float fm = (m == 0) ? fv.x : (m == 1) ? fv.y : (m == 2) ? fv.z : fv.w;
            const float4* wrow = (const float4*)(wr + m * HF);   // wave-uniform addr
            float4 w0 = wrow[0], w1 = wrow[1], w2 = wrow[2], w3 = wrow[3];
            FMA4(acc0, fm, w0);
            FMA4(acc1, fm, w1);
            FMA4(acc2, fm, w2);
            FMA4(acc3, fm, w3);
        }
    }

    __syncthreads();   // all waves done READING W1 planes; safe to alias
    {   // red[w][lane][16] in the first 32 KB of smem
        float4* rp = (float4*)(smem + ((w * 64 + lane) << 4));
        rp[0] = acc0; rp[1] = acc1; rp[2] = acc2; rp[3] = acc3;
    }
    __syncthreads();

    if (t < 256) {   // thread t: row r = t>>2, j-quad q = t&3 ; sum the 8 k-slices
        const int r = t >> 2, q = t & 3;
        float4 s = {0,0,0,0};
#pragma unroll
        for (int ww = 0; ww < 8; ++ww) {
            float4 p = *(const float4*)(smem + ((ww * 64 + r) << 4) + q * 4);
            s.x += p.x; s.y += p.y; s.z += p.z; s.w += p.w;
        }
        const int orow = blockIdx.x * 64 + r;
        if (orow < NN)
            *(float4*)(P + (size_t)orow * HF + q * 4) = s;
    }
}

// -----------------------------------------------------------------------------
// agg1: A1[n] = sum_{e into n} P[src[e]]. 16 lanes per node: 4 edge-subgroups
// (es) x 4 float4-lanes (q). Butterfly xor 4,8 merges edge groups.
// -----------------------------------------------------------------------------
__global__ __launch_bounds__(256) void agg1_kernel(const float* __restrict__ P,
                                                   const int* __restrict__ cnt,
                                                   const int* __restrict__ ell,
                                                   float* __restrict__ A1) {
    int g = blockIdx.x * 256 + threadIdx.x;
    int node = g >> 4;
    if (node >= NN) return;
    const int l = g & 15, es = l >> 2, q = l & 3;
    int c = cnt[node]; if (c > ELLW) c = ELLW;
    const int* ep = ell + node * ELLW;

    float4 v = {0,0,0,0};
    for (int i = es; i < c; i += 4) {
        int s = ep[i];
        float4 p = *(const float4*)(P + (size_t)s * HF + q * 4);
        v.x += p.x; v.y += p.y; v.z += p.z; v.w += p.w;
    }
#define BFLY2(VAL) { VAL += __shfl_xor(VAL, 4); VAL += __shfl_xor(VAL, 8); }
    BFLY2(v.x) BFLY2(v.y) BFLY2(v.z) BFLY2(v.w)
#undef BFLY2
    if (es == 0)
        *(float4*)(A1 + (size_t)node * HF + q * 4) = v;
}

// -----------------------------------------------------------------------------
// agg2 + output GEMM fused: A2[n] = sum relu(A1[src]+b1) (16 lanes/node),
// then out[n] = A2 @ W2 + b2 via per-q partials + xor 1,2 butterfly.
// -----------------------------------------------------------------------------
__global__ __launch_bounds__(256) void agg2out_kernel(const float* __restrict__ A1,
                                                      const float* __restrict__ b1,
                                                      const int* __restrict__ cnt,
                                                      const int* __restrict__ ell,
                                                      const float* __restrict__ W2,
                                                      const float* __restrict__ b2,
                                                      float* __restrict__ out) {
    __shared__ float W2s[HF * OF];
    __shared__ float b2s[OF];
    const int t = threadIdx.x;
    for (int i = t; i < HF * OF; i += 256) W2s[i] = W2[i];
    if (t < OF) b2s[t] = b2[t];
    __syncthreads();

    int g = blockIdx.x * 256 + t;
    int node = g >> 4;
    if (node >= NN) return;
    const int l = g & 15, es = l >> 2, q = l & 3;

    const float4 bb = *(const float4*)(b1 + q * 4);
    int c = cnt[node]; if (c > ELLW) c = ELLW;
    const int* ep = ell + node * ELLW;

    float4 v = {0,0,0,0};
    for (int i = es; i < c; i += 4) {
        int s = ep[i];
        float4 h = *(const float4*)(A1 + (size_t)s * HF + q * 4);
        h.x = fmaxf(h.x + bb.x, 0.0f);
        h.y = fmaxf(h.y + bb.y, 0.0f);
        h.z = fmaxf(h.z + bb.z, 0.0f);
        h.w = fmaxf(h.w + bb.w, 0.0f);
        v.x += h.x; v.y += h.y; v.z += h.z; v.w += h.w;
    }
#define BFLY2(VAL) { VAL += __shfl_xor(VAL, 4); VAL += __shfl_xor(VAL, 8); }
    BFLY2(v.x) BFLY2(v.y) BFLY2(v.z) BFLY2(v.w)
#undef BFLY2

    const float* w0 = W2s + (q * 4 + 0) * OF;
    const float* w1 = W2s + (q * 4 + 1) * OF;
    const float* w2 = W2s + (q * 4 + 2) * OF;
    const float* w3 = W2s + (q * 4 + 3) * OF;
    float o[OF];
#pragma unroll
    for (int cc = 0; cc < OF; ++cc)
        o[cc] = v.x * w0[cc] + v.y * w1[cc] + v.z * w2[cc] + v.w * w3[cc];
#pragma unroll
    for (int cc = 0; cc < OF; ++cc) {
        o[cc] += __shfl_xor(o[cc], 1);
        o[cc] += __shfl_xor(o[cc], 2);
    }
    if (es == 0) {
        float* op = out + (size_t)node * OF;
        for (int cc = q; cc < OF; cc += 4) op[cc] = o[cc] + b2s[cc];
    }
}

extern "C" void kernel_launch(void* const* d_in, const int* in_sizes, int n_in,
                              void* d_out, int out_size, void* d_ws, size_t ws_size,
                              hipStream_t stream) {
    const float* F   = (const float*)d_in[0];
    const float* W1  = (const float*)d_in[1];
    const float* b1  = (const float*)d_in[2];
    const float* W2  = (const float*)d_in[3];
    const float* b2  = (const float*)d_in[4];
    const int*   src = (const int*)d_in[5];
    const int*   dst = (const int*)d_in[6];
    float* out = (float*)d_out;

    char* ws = (char*)d_ws;
    int*   cnt = (int*)(ws);                       // 200,000 B
    int*   ell = (int*)(ws + 200192);              // 8,000,000 B
    float* P   = (float*)(ws + 8200192);           // 3,200,000 B
    float* A1  = (float*)(ws + 11400192);          // 3,200,000 B

    (void)hipMemsetAsync(cnt, 0, NN * sizeof(int), stream);
    scatter_kernel<<<(NE + 255) / 256, 256, 0, stream>>>(src, dst, cnt, ell);
    gemm1_kernel<<<(NN + 63) / 64, 512, 0, stream>>>(F, W1, P);
    agg1_kernel<<<(NN * 16 + 255) / 256, 256, 0, stream>>>(P, cnt, ell, A1);
    agg2out_kernel<<<(NN * 16 + 255) / 256, 256, 0, stream>>>(A1, b1, cnt, ell, W2, b2, out);
}